// Round 7
// baseline (613.432 us; speedup 1.0000x reference)
//
#include <hip/hip_runtime.h>

static __device__ __forceinline__ float silu_f(float v) {
    return v / (1.0f + __expf(-v));
}

// ---------------- bucketed CSR build ----------------

extern "C" __global__ __launch_bounds__(256) void k_bhist(
    const int* __restrict__ dst, int* __restrict__ bcount, int E, int nbkt, int shift)
{
    __shared__ int lh[512];
    int t = threadIdx.x;
    for (int i = t; i < 512; i += 256) lh[i] = 0;
    __syncthreads();
    int e0 = blockIdx.x * 8192;
    #pragma unroll 4
    for (int i = 0; i < 32; i++) {
        int e = e0 + t + i * 256;
        if (e < E) atomicAdd(&lh[dst[e] >> shift], 1);
    }
    __syncthreads();
    for (int b = t; b < nbkt; b += 256)
        if (lh[b]) atomicAdd(&bcount[b], lh[b]);
}

extern "C" __global__ __launch_bounds__(512) void k_bscan(
    const int* __restrict__ bcount, int* __restrict__ boff, int* __restrict__ bcursor, int nbkt)
{
    __shared__ int sc[512];
    int t = threadIdx.x;
    int v = (t < nbkt) ? bcount[t] : 0;
    sc[t] = v;
    __syncthreads();
    for (int off = 1; off < 512; off <<= 1) {
        int add = (t >= off) ? sc[t - off] : 0;
        __syncthreads();
        sc[t] += add;
        __syncthreads();
    }
    int excl = sc[t] - v;
    if (t < nbkt) { boff[t] = excl; bcursor[t] = excl; }
    if (t == nbkt - 1) boff[nbkt] = excl + v;
}

extern "C" __global__ __launch_bounds__(256) void k_bscatter(
    const int* __restrict__ src, const int* __restrict__ dst, int* __restrict__ bcursor,
    int2* __restrict__ ebuf, int E, int nbkt, int shift)
{
    __shared__ int lh[512];
    __shared__ int lbase[512];
    int t = threadIdx.x;
    for (int i = t; i < 512; i += 256) lh[i] = 0;
    __syncthreads();
    int e0 = blockIdx.x * 8192;
    #pragma unroll 4
    for (int i = 0; i < 32; i++) {
        int e = e0 + t + i * 256;
        if (e < E) atomicAdd(&lh[dst[e] >> shift], 1);
    }
    __syncthreads();
    for (int b = t; b < nbkt; b += 256)
        lbase[b] = lh[b] ? atomicAdd(&bcursor[b], lh[b]) : 0;
    __syncthreads();
    #pragma unroll 4
    for (int i = 0; i < 32; i++) {
        int e = e0 + t + i * 256;
        if (e < E) {
            int d = dst[e];
            int p = atomicAdd(&lbase[d >> shift], 1);
            ebuf[p] = make_int2(src[e], d);
        }
    }
}

extern "C" __global__ __launch_bounds__(256) void k_bdeg(
    const int2* __restrict__ ebuf, const int* __restrict__ boff,
    int* __restrict__ deg, int shift, int N)
{
    int b = blockIdx.x;
    int W = 1 << shift;
    __shared__ int lcur[4096];
    int t = threadIdx.x;
    for (int i = t; i < W; i += 256) lcur[i] = 0;
    __syncthreads();
    int s = boff[b], e_ = boff[b + 1];
    for (int e = s + t; e < e_; e += 256)
        atomicAdd(&lcur[ebuf[e].y - (b << shift)], 1);
    __syncthreads();
    int base = b << shift;
    for (int i = t; i < W; i += 256) {
        int node = base + i;
        if (node < N) deg[node] = lcur[i];
    }
}

extern "C" __global__ __launch_bounds__(256) void k_bfill(
    const int2* __restrict__ ebuf, const int* __restrict__ boff,
    const int* __restrict__ rowstart, int* __restrict__ csr, int shift)
{
    int b = blockIdx.x;
    int W = 1 << shift;
    __shared__ int lcur[4096];
    int t = threadIdx.x;
    for (int i = t; i < W; i += 256) lcur[i] = 0;
    __syncthreads();
    int s = boff[b], e_ = boff[b + 1];
    for (int e = s + t; e < e_; e += 256) {
        int2 p = ebuf[e];
        int pos = atomicAdd(&lcur[p.y - (b << shift)], 1);
        csr[rowstart[p.y] + pos] = p.x;
    }
}

// ---------------- degree-scan (rowstart) ----------------

extern "C" __global__ void k_dinv(const int* __restrict__ deg, float* __restrict__ dinv, int n) {
    int i = blockIdx.x * 256 + threadIdx.x;
    if (i < n) dinv[i] = rsqrtf((float)(deg[i] + 1));   // +1 = self loop
}

extern "C" __global__ void k_scan_partial(const int* __restrict__ deg, int* __restrict__ bsum, int n) {
    int base = blockIdx.x * 1024;
    int s = 0;
    for (int i = threadIdx.x; i < 1024; i += 256) {
        int idx = base + i;
        s += (idx < n) ? deg[idx] : 0;
    }
    for (int off = 1; off < 64; off <<= 1) s += __shfl_xor(s, off, 64);
    __shared__ int wsum[4];
    if ((threadIdx.x & 63) == 0) wsum[threadIdx.x >> 6] = s;
    __syncthreads();
    if (threadIdx.x == 0) bsum[blockIdx.x] = wsum[0] + wsum[1] + wsum[2] + wsum[3];
}

extern "C" __global__ void k_scan_bsum(int* __restrict__ bsum, int nb) {
    if (threadIdx.x == 0 && blockIdx.x == 0) {
        int run = 0;
        for (int i = 0; i < nb; i++) { int v = bsum[i]; bsum[i] = run; run += v; }
    }
}

extern "C" __global__ void k_scan_write(const int* __restrict__ deg, const int* __restrict__ bsum,
                                        int* __restrict__ rowstart, int n) {
    int t = threadIdx.x;
    int base = blockIdx.x * 1024;
    int v[4], loc[4];
    int s = 0;
    #pragma unroll
    for (int i = 0; i < 4; i++) {
        int idx = base + t * 4 + i;
        v[i] = (idx < n) ? deg[idx] : 0;
        loc[i] = s; s += v[i];
    }
    __shared__ int sc[256];
    sc[t] = s;
    __syncthreads();
    int mine = s;
    for (int off = 1; off < 256; off <<= 1) {
        int add = (t >= off) ? sc[t - off] : 0;
        __syncthreads();
        sc[t] += add;
        __syncthreads();
    }
    int excl = sc[t] - mine + bsum[blockIdx.x];
    #pragma unroll
    for (int i = 0; i < 4; i++) {
        int idx = base + t * 4 + i;
        if (idx < n) rowstart[idx] = excl + loc[i];
    }
}

// ---------------- W pre-transpose: wTg[c][k] = [W1|Wr1][k][c] ----------------
extern "C" __global__ __launch_bounds__(256) void k_wt(
    const float* __restrict__ W1, const float* __restrict__ Wr1, float* __restrict__ wTg)
{
    int id = blockIdx.x * 256 + threadIdx.x;   // 16384 elements
    int k = id >> 7, c = id & 127;
    float v = (c < 64) ? W1[k * 64 + c] : Wr1[k * 64 + (c - 64)];
    wTg[c * 128 + k] = v;
}

// ---------------- gemm1: h0s = (x@W1)*dinv ; r1 = silu(x@Wr1+br1) ----------------
// 128x128 tile, 512 threads, per-thread 4x8.
// Slot swizzle p = kq ^ (row&7) ^ ((row>>3)&7): store-side conflict-free
// (8 lanes per kq span 8 bank-quads), read-side x conflict-free / w 2-way (free).
// __launch_bounds__(512,2): min 2 waves/EU -> 256-VGPR budget -> no spill.
extern "C" __global__ __launch_bounds__(512, 2) void k_gemm1(
    const float* __restrict__ x, const float* __restrict__ wTg,
    const float* __restrict__ br1, const float* __restrict__ dinv,
    float* __restrict__ h0s, float* __restrict__ r1, int n)
{
    __shared__ float xs[128 * 32];   // [row][8 f4 slots], slot = kq ^ (row&7) ^ ((row>>3)&7)
    __shared__ float wT[128 * 32];   // [c][8 f4 slots],   slot = kq ^ (c&7) ^ ((c>>3)&7)
    int t = threadIdx.x;
    int r0 = blockIdx.x * 128;
    int rg = t >> 4;                 // 0..31 : rows rg*4..+3
    int cg = t & 15;                 // 0..15 : cols cg*8..+7

    float acc[4][8] = {};
    float4 px[2], pw[2];

    // chunk 0 prefetch (1024 f4 each side, 2 per thread)
    #pragma unroll
    for (int i = 0; i < 2; i++) {
        int idx = t + i * 512, row = idx >> 3, kq = idx & 7;
        int grow = r0 + row;
        px[i] = (grow < n) ? *(const float4*)&x[(size_t)grow * 128 + kq * 4]
                           : make_float4(0.f, 0.f, 0.f, 0.f);
        pw[i] = *(const float4*)&wTg[(size_t)row * 128 + kq * 4];   // row == c here
    }

    // read-side swizzle components (runtime, wave-uniform-ish)
    const int r4   = rg * 4;
    const int xsw  = (((rg & 1) * 4) ^ ((rg >> 1) & 7)) * 4;  // s(row)*4 minus the i part
    const int cgl4 = (cg & 7) * 4;                            // (c>>3)&7 = cg&7, times 4

    for (int kk = 0; kk < 128; kk += 32) {
        if (kk) __syncthreads();
        #pragma unroll
        for (int i = 0; i < 2; i++) {
            int idx = t + i * 512, row = idx >> 3, kq = idx & 7;
            int p = kq ^ (row & 7) ^ ((row >> 3) & 7);
            *(float4*)&xs[row * 32 + p * 4] = px[i];
            *(float4*)&wT[row * 32 + p * 4] = pw[i];   // same (row==c) swizzle
        }
        __syncthreads();
        if (kk < 96) {   // prefetch next chunk; latency hidden under inner loop
            int kn = kk + 32;
            #pragma unroll
            for (int i = 0; i < 2; i++) {
                int idx = t + i * 512, row = idx >> 3, kq = idx & 7;
                int grow = r0 + row;
                px[i] = (grow < n) ? *(const float4*)&x[(size_t)grow * 128 + kn + kq * 4]
                                   : make_float4(0.f, 0.f, 0.f, 0.f);
                pw[i] = *(const float4*)&wTg[(size_t)row * 128 + kn + kq * 4];
            }
        }
        #pragma unroll
        for (int k4 = 0; k4 < 8; k4++) {
            float4 xv[4];
            #pragma unroll
            for (int i = 0; i < 4; i++) {
                // addr = (r4+i)*32 + ((i ^ k4)*4 ^ xsw)
                xv[i] = *(const float4*)&xs[(r4 + i) * 32 + (((i ^ k4) * 4) ^ xsw)];
            }
            #pragma unroll
            for (int j = 0; j < 8; j++) {
                // addr = (cg*8+j)*32 + ((j ^ k4)*4 ^ cgl4)
                float4 wv = *(const float4*)&wT[(cg * 8 + j) * 32 + (((j ^ k4) * 4) ^ cgl4)];
                #pragma unroll
                for (int i = 0; i < 4; i++) {
                    acc[i][j] += xv[i].x * wv.x + xv[i].y * wv.y
                               + xv[i].z * wv.z + xv[i].w * wv.w;
                }
            }
        }
    }

    if (cg < 8) {                    // h0s cols 0..63
        int c0 = cg * 8;
        #pragma unroll
        for (int i = 0; i < 4; i++) {
            int row = r0 + rg * 4 + i;
            if (row >= n) break;
            float dv = dinv[row];
            float4 o0 = make_float4(acc[i][0]*dv, acc[i][1]*dv, acc[i][2]*dv, acc[i][3]*dv);
            float4 o1 = make_float4(acc[i][4]*dv, acc[i][5]*dv, acc[i][6]*dv, acc[i][7]*dv);
            *(float4*)&h0s[(size_t)row * 64 + c0]     = o0;
            *(float4*)&h0s[(size_t)row * 64 + c0 + 4] = o1;
        }
    } else {                         // r1 cols 0..63
        int c0 = cg * 8 - 64;
        float bb[8];
        #pragma unroll
        for (int q = 0; q < 8; q++) bb[q] = br1[c0 + q];
        #pragma unroll
        for (int i = 0; i < 4; i++) {
            int row = r0 + rg * 4 + i;
            if (row >= n) break;
            float4 o0 = make_float4(silu_f(acc[i][0]+bb[0]), silu_f(acc[i][1]+bb[1]),
                                    silu_f(acc[i][2]+bb[2]), silu_f(acc[i][3]+bb[3]));
            float4 o1 = make_float4(silu_f(acc[i][4]+bb[4]), silu_f(acc[i][5]+bb[5]),
                                    silu_f(acc[i][6]+bb[6]), silu_f(acc[i][7]+bb[7]));
            *(float4*)&r1[(size_t)row * 64 + c0]     = o0;
            *(float4*)&r1[(size_t)row * 64 + c0 + 4] = o1;
        }
    }
}

// h = silu(dinv[dst]*(sum_src h0s + h0s[dst]) + b1) + r1*alpha1 ; in place over r1
extern "C" __global__ __launch_bounds__(256) void k_agg1(
    const float* __restrict__ h0s, const int* __restrict__ rowstart, const int* __restrict__ deg,
    const int* __restrict__ csr, const float* __restrict__ dinv, const float* __restrict__ b1,
    const float* __restrict__ alpha1, float* __restrict__ r1h, int n)
{
    int wave = threadIdx.x >> 6, lane = threadIdx.x & 63;
    int node = blockIdx.x * 4 + wave;
    if (node >= n) return;
    int rs = rowstart[node];
    int cnt = deg[node];
    float acc = h0s[(size_t)node * 64 + lane];   // self loop
    int i = 0;
    for (; i + 8 <= cnt; i += 8) {
        int s0 = csr[rs+i+0], s1 = csr[rs+i+1], s2 = csr[rs+i+2], s3 = csr[rs+i+3];
        int s4 = csr[rs+i+4], s5 = csr[rs+i+5], s6 = csr[rs+i+6], s7 = csr[rs+i+7];
        float a0 = h0s[(size_t)s0*64+lane], a1 = h0s[(size_t)s1*64+lane];
        float a2 = h0s[(size_t)s2*64+lane], a3 = h0s[(size_t)s3*64+lane];
        float a4 = h0s[(size_t)s4*64+lane], a5 = h0s[(size_t)s5*64+lane];
        float a6 = h0s[(size_t)s6*64+lane], a7 = h0s[(size_t)s7*64+lane];
        acc += ((a0+a1)+(a2+a3)) + ((a4+a5)+(a6+a7));
    }
    for (; i < cnt; i++) acc += h0s[(size_t)csr[rs+i]*64+lane];
    float v = dinv[node] * acc + b1[lane];
    float hv = silu_f(v) + r1h[(size_t)node * 64 + lane] * alpha1[0];
    r1h[(size_t)node * 64 + lane] = hv;
}

// h2s = (h @ W2) * dinv ; r2 = silu(h @ Wr2 + br2)
extern "C" __global__ __launch_bounds__(256) void k_gemm2(
    const float* __restrict__ h, const float* __restrict__ W2, const float* __restrict__ Wr2,
    const float* __restrict__ br2, const float* __restrict__ dinv,
    float* __restrict__ h2s, float* __restrict__ r2, int n)
{
    __shared__ float xsT[64 * 132];   // [k][row]
    __shared__ float wsm[64 * 32];    // [k][c]
    int t = threadIdx.x;
    int r0 = blockIdx.x * 128;
    int rg = t >> 3;                  // 0..31, rows rg*4..+3
    int cg = t & 7;                   // cols cg*4..+3
    float acc[4][4] = {};

    #pragma unroll
    for (int i = 0; i < 8; i++) {     // stage h transposed: 2048 float4
        int u = t + i * 256;
        int row = u >> 4, kq = u & 15;
        float4 v = make_float4(0.f, 0.f, 0.f, 0.f);
        int grow = r0 + row;
        if (grow < n) v = *(const float4*)&h[(size_t)grow * 64 + kq * 4];
        xsT[(kq * 4 + 0) * 132 + row] = v.x;
        xsT[(kq * 4 + 1) * 132 + row] = v.y;
        xsT[(kq * 4 + 2) * 132 + row] = v.z;
        xsT[(kq * 4 + 3) * 132 + row] = v.w;
    }
    #pragma unroll
    for (int i = 0; i < 2; i++) {     // stage [W2|Wr2]: 512 float4
        int ul = t + i * 256;
        int k = ul >> 3, u = ul & 7;
        int c = u * 4;
        float4 v;
        if (c < 16) v = *(const float4*)&W2[(size_t)k * 16 + c];
        else        v = *(const float4*)&Wr2[(size_t)k * 16 + (c - 16)];
        *(float4*)&wsm[k * 32 + c] = v;
    }
    __syncthreads();

    const float* xbase = &xsT[rg * 4];
    const float* wbase = &wsm[cg * 4];
    #pragma unroll
    for (int k = 0; k < 64; k++) {
        float4 xa = *(const float4*)&xbase[k * 132];
        float4 wa = *(const float4*)&wbase[k * 32];
        float xv[4] = {xa.x, xa.y, xa.z, xa.w};
        float wv[4] = {wa.x, wa.y, wa.z, wa.w};
        #pragma unroll
        for (int i = 0; i < 4; i++)
            #pragma unroll
            for (int j = 0; j < 4; j++) acc[i][j] += xv[i] * wv[j];
    }

    if (cg < 4) {                     // h2s cols 0..15
        int c0 = cg * 4;
        #pragma unroll
        for (int i = 0; i < 4; i++) {
            int row = r0 + rg * 4 + i;
            if (row >= n) break;
            float dv = dinv[row];
            float4 o = make_float4(acc[i][0]*dv, acc[i][1]*dv, acc[i][2]*dv, acc[i][3]*dv);
            *(float4*)&h2s[(size_t)row * 16 + c0] = o;
        }
    } else {                          // r2 cols 0..15
        int c0 = (cg - 4) * 4;
        float4 b = *(const float4*)&br2[c0];
        #pragma unroll
        for (int i = 0; i < 4; i++) {
            int row = r0 + rg * 4 + i;
            if (row >= n) break;
            float4 o = make_float4(silu_f(acc[i][0]+b.x), silu_f(acc[i][1]+b.y),
                                   silu_f(acc[i][2]+b.z), silu_f(acc[i][3]+b.w));
            *(float4*)&r2[(size_t)row * 16 + c0] = o;
        }
    }
}

// z = dinv[dst]*(sum h2s + h2s[dst]) + b2 + r2*alpha2 ; in place over r2
extern "C" __global__ __launch_bounds__(256) void k_agg2(
    const float* __restrict__ h2s, const int* __restrict__ rowstart, const int* __restrict__ deg,
    const int* __restrict__ csr, const float* __restrict__ dinv, const float* __restrict__ b2,
    const float* __restrict__ alpha2, float* __restrict__ r2z, int n)
{
    int wave = threadIdx.x >> 6, lane = threadIdx.x & 63;
    int node = blockIdx.x * 4 + wave;
    if (node >= n) return;
    int rs = rowstart[node], cnt = deg[node];
    int sub = lane >> 4, j = lane & 15;
    float acc = 0.0f;
    int i = sub;
    for (; i + 8 <= cnt; i += 8) {
        int sa = csr[rs + i], sb = csr[rs + i + 4];
        acc += h2s[(size_t)sa * 16 + j] + h2s[(size_t)sb * 16 + j];
    }
    for (; i < cnt; i += 4) acc += h2s[(size_t)csr[rs + i] * 16 + j];
    acc += __shfl_xor(acc, 16, 64);
    acc += __shfl_xor(acc, 32, 64);
    if (sub == 0) {
        acc += h2s[(size_t)node * 16 + j];
        float v = dinv[node] * acc + b2[j] + r2z[(size_t)node * 16 + j] * alpha2[0];
        r2z[(size_t)node * 16 + j] = v;
    }
}

// graph mean pool
extern "C" __global__ __launch_bounds__(256) void k_pool(
    const float* __restrict__ z, const int* __restrict__ batch, float* __restrict__ emb, int n)
{
    int g = blockIdx.x;
    int lo = 0, hi = n;
    while (lo < hi) { int m = (lo + hi) >> 1; if (batch[m] < g) lo = m + 1; else hi = m; }
    int start = lo;
    lo = start; hi = n;
    while (lo < hi) { int m = (lo + hi) >> 1; if (batch[m] < g + 1) lo = m + 1; else hi = m; }
    int end = lo;
    int j = threadIdx.x & 15, grp = threadIdx.x >> 4;
    float acc = 0.0f;
    for (int r = start + grp; r < end; r += 16) acc += z[(size_t)r * 16 + j];
    __shared__ float part[16][17];
    part[grp][j] = acc;
    __syncthreads();
    if (threadIdx.x < 16) {
        float s = 0.0f;
        #pragma unroll
        for (int q = 0; q < 16; q++) s += part[q][threadIdx.x];
        float cnt = (float)(end - start);
        emb[g * 16 + threadIdx.x] = s / fmaxf(cnt, 1.0f);
    }
}

extern "C" __global__ void k_metrics(
    const float* __restrict__ tol, const float* __restrict__ cost,
    const float* __restrict__ time_, const float* __restrict__ qty,
    const float* __restrict__ mW1, const float* __restrict__ mb1,
    const float* __restrict__ mW2, const float* __restrict__ mb2,
    float* __restrict__ metrics)
{
    int t = threadIdx.x;
    if (t >= 64) return;
    int i = t >> 4, j = t & 15;
    float mv = (i == 0) ? tol[0] : (i == 1) ? cost[0] : (i == 2) ? time_[0] : qty[0];
    float acc = mb2[i * 16 + j];
    #pragma unroll
    for (int k = 0; k < 8; k++) {
        float hpre = mv * mW1[i * 8 + k] + mb1[i * 8 + k];
        acc += silu_f(hpre) * mW2[i * 128 + k * 16 + j];
    }
    metrics[t] = acc;
}

extern "C" __global__ __launch_bounds__(128) void k_head(
    const float* __restrict__ emb, const float* __restrict__ metrics,
    const float* __restrict__ Wf1, const float* __restrict__ bf1,
    const float* __restrict__ Wf2, const float* __restrict__ bf2,
    float* __restrict__ out, int NC)
{
    int g = blockIdx.x;
    __shared__ float c[80], hidden[80];
    int t = threadIdx.x;
    if (t < 16) c[t] = emb[g * 16 + t];
    else if (t < 80) c[t] = metrics[t - 16];
    __syncthreads();
    if (t < 80) {
        float acc = bf1[t];
        #pragma unroll 8
        for (int k = 0; k < 80; k++) acc += c[k] * Wf1[k * 80 + t];
        hidden[t] = silu_f(acc);
    }
    __syncthreads();
    if (t < NC) {
        float acc = bf2[t];
        #pragma unroll 8
        for (int k = 0; k < 80; k++) acc += hidden[k] * Wf2[k * NC + t];
        out[g * NC + t] = acc;
    }
}

extern "C" void kernel_launch(void* const* d_in, const int* in_sizes, int n_in,
                              void* d_out, int out_size, void* d_ws, size_t ws_size,
                              hipStream_t stream)
{
    const float* x     = (const float*)d_in[0];
    const int*   ei    = (const int*)d_in[1];
    const int*   batch = (const int*)d_in[2];
    const float* tol   = (const float*)d_in[3];
    const float* cost  = (const float*)d_in[4];
    const float* time_ = (const float*)d_in[5];
    const float* qty   = (const float*)d_in[6];
    const float* W1    = (const float*)d_in[7];
    const float* b1    = (const float*)d_in[8];
    const float* W2    = (const float*)d_in[9];
    const float* b2    = (const float*)d_in[10];
    const float* Wr1   = (const float*)d_in[11];
    const float* br1   = (const float*)d_in[12];
    const float* Wr2   = (const float*)d_in[13];
    const float* br2   = (const float*)d_in[14];
    const float* alpha1= (const float*)d_in[15];
    const float* alpha2= (const float*)d_in[16];
    const float* mW1   = (const float*)d_in[17];
    const float* mb1   = (const float*)d_in[18];
    const float* mW2   = (const float*)d_in[19];
    const float* mb2   = (const float*)d_in[20];
    const float* Wf1   = (const float*)d_in[21];
    const float* bf1   = (const float*)d_in[22];
    const float* Wf2   = (const float*)d_in[23];
    const float* bf2   = (const float*)d_in[24];

    const int N  = in_sizes[2];
    const int E  = in_sizes[1] / 2;
    const int NC = in_sizes[24];
    const int G  = out_size / NC;

    const int* srcIdx = ei;
    const int* dstIdx = ei + E;

    int shift = 8;
    while (((N + (1 << shift) - 1) >> shift) > 512) shift++;
    const int nbkt = (N + (1 << shift) - 1) >> shift;

    char* w = (char*)d_ws;
    auto alloc = [&](size_t bytes) { char* p = w; w += (bytes + 255) & ~(size_t)255; return p; };
    int*   deg      = (int*)alloc((size_t)N * 4);
    int*   rowstart = (int*)alloc((size_t)N * 4);
    int*   bcount   = (int*)alloc(2048);
    int*   boff     = (int*)alloc(2052 + 252);
    int*   bcursor  = (int*)alloc(2048);
    int*   bsum     = (int*)alloc(4096);
    int*   csr      = (int*)alloc((size_t)E * 4);
    int2*  ebuf     = (int2*)alloc((size_t)E * 8);
    float* dinv     = (float*)alloc((size_t)N * 4);
    float* wTg      = (float*)alloc(128 * 128 * 4);
    float* bufA     = (float*)alloc((size_t)N * 64 * 4);  // h0s, later h2s
    float* bufB     = (float*)alloc((size_t)N * 64 * 4);  // r1, later h (in place)
    float* bufC     = (float*)alloc((size_t)N * 16 * 4);  // r2, later z (in place)
    float* emb      = (float*)alloc((size_t)G * 16 * 4);
    float* metricsv = (float*)alloc(256);

    hipMemsetAsync(bcount, 0, 2048, stream);

    int EB8 = (E + 8191) / 8192;
    int nb  = (N + 255) / 256;
    int NB  = (N + 1023) / 1024;

    k_wt      <<<64, 256, 0, stream>>>(W1, Wr1, wTg);
    k_bhist   <<<EB8, 256, 0, stream>>>(dstIdx, bcount, E, nbkt, shift);
    k_bscan   <<<1, 512, 0, stream>>>(bcount, boff, bcursor, nbkt);
    k_bscatter<<<EB8, 256, 0, stream>>>(srcIdx, dstIdx, bcursor, ebuf, E, nbkt, shift);
    k_bdeg    <<<nbkt, 256, 0, stream>>>(ebuf, boff, deg, shift, N);
    k_dinv    <<<nb, 256, 0, stream>>>(deg, dinv, N);
    k_scan_partial<<<NB, 256, 0, stream>>>(deg, bsum, N);
    k_scan_bsum   <<<1, 64, 0, stream>>>(bsum, NB);
    k_scan_write  <<<NB, 256, 0, stream>>>(deg, bsum, rowstart, N);
    k_bfill   <<<nbkt, 256, 0, stream>>>(ebuf, boff, rowstart, csr, shift);

    k_gemm1<<<(N + 127) / 128, 512, 0, stream>>>(x, wTg, br1, dinv, bufA, bufB, N);
    k_agg1 <<<(N + 3) / 4, 256, 0, stream>>>(bufA, rowstart, deg, csr, dinv, b1, alpha1, bufB, N);
    k_gemm2<<<(N + 127) / 128, 256, 0, stream>>>(bufB, W2, Wr2, br2, dinv, bufA, bufC, N);
    k_agg2 <<<(N + 3) / 4, 256, 0, stream>>>(bufA, rowstart, deg, csr, dinv, b2, alpha2, bufC, N);
    k_pool <<<G, 256, 0, stream>>>(bufC, batch, emb, N);
    k_metrics<<<1, 64, 0, stream>>>(tol, cost, time_, qty, mW1, mb1, mW2, mb2, metricsv);
    k_head <<<G, 128, 0, stream>>>(emb, metricsv, Wf1, bf1, Wf2, bf2, (float*)d_out, NC);
}

// Round 8
// 310.665 us; speedup vs baseline: 1.9746x; 1.9746x over previous
//
#include <hip/hip_runtime.h>

static __device__ __forceinline__ float silu_f(float v) {
    return v / (1.0f + __expf(-v));
}

// ---------------- bucketed CSR build ----------------

extern "C" __global__ __launch_bounds__(256) void k_bhist(
    const int* __restrict__ dst, int* __restrict__ bcount, int E, int nbkt, int shift)
{
    __shared__ int lh[512];
    int t = threadIdx.x;
    for (int i = t; i < 512; i += 256) lh[i] = 0;
    __syncthreads();
    int e0 = blockIdx.x * 8192;
    #pragma unroll 4
    for (int i = 0; i < 32; i++) {
        int e = e0 + t + i * 256;
        if (e < E) atomicAdd(&lh[dst[e] >> shift], 1);
    }
    __syncthreads();
    for (int b = t; b < nbkt; b += 256)
        if (lh[b]) atomicAdd(&bcount[b], lh[b]);
}

extern "C" __global__ __launch_bounds__(512) void k_bscan(
    const int* __restrict__ bcount, int* __restrict__ boff, int* __restrict__ bcursor, int nbkt)
{
    __shared__ int sc[512];
    int t = threadIdx.x;
    int v = (t < nbkt) ? bcount[t] : 0;
    sc[t] = v;
    __syncthreads();
    for (int off = 1; off < 512; off <<= 1) {
        int add = (t >= off) ? sc[t - off] : 0;
        __syncthreads();
        sc[t] += add;
        __syncthreads();
    }
    int excl = sc[t] - v;
    if (t < nbkt) { boff[t] = excl; bcursor[t] = excl; }
    if (t == nbkt - 1) boff[nbkt] = excl + v;
}

extern "C" __global__ __launch_bounds__(256) void k_bscatter(
    const int* __restrict__ src, const int* __restrict__ dst, int* __restrict__ bcursor,
    int2* __restrict__ ebuf, int E, int nbkt, int shift)
{
    __shared__ int lh[512];
    __shared__ int lbase[512];
    int t = threadIdx.x;
    for (int i = t; i < 512; i += 256) lh[i] = 0;
    __syncthreads();
    int e0 = blockIdx.x * 8192;
    #pragma unroll 4
    for (int i = 0; i < 32; i++) {
        int e = e0 + t + i * 256;
        if (e < E) atomicAdd(&lh[dst[e] >> shift], 1);
    }
    __syncthreads();
    for (int b = t; b < nbkt; b += 256)
        lbase[b] = lh[b] ? atomicAdd(&bcursor[b], lh[b]) : 0;
    __syncthreads();
    #pragma unroll 4
    for (int i = 0; i < 32; i++) {
        int e = e0 + t + i * 256;
        if (e < E) {
            int d = dst[e];
            int p = atomicAdd(&lbase[d >> shift], 1);
            ebuf[p] = make_int2(src[e], d);
        }
    }
}

extern "C" __global__ __launch_bounds__(256) void k_bdeg(
    const int2* __restrict__ ebuf, const int* __restrict__ boff,
    int* __restrict__ deg, int shift, int N)
{
    int b = blockIdx.x;
    int W = 1 << shift;
    __shared__ int lcur[4096];
    int t = threadIdx.x;
    for (int i = t; i < W; i += 256) lcur[i] = 0;
    __syncthreads();
    int s = boff[b], e_ = boff[b + 1];
    for (int e = s + t; e < e_; e += 256)
        atomicAdd(&lcur[ebuf[e].y - (b << shift)], 1);
    __syncthreads();
    int base = b << shift;
    for (int i = t; i < W; i += 256) {
        int node = base + i;
        if (node < N) deg[node] = lcur[i];
    }
}

extern "C" __global__ __launch_bounds__(256) void k_bfill(
    const int2* __restrict__ ebuf, const int* __restrict__ boff,
    const int* __restrict__ rowstart, int* __restrict__ csr, int shift)
{
    int b = blockIdx.x;
    int W = 1 << shift;
    __shared__ int lcur[4096];
    int t = threadIdx.x;
    for (int i = t; i < W; i += 256) lcur[i] = 0;
    __syncthreads();
    int s = boff[b], e_ = boff[b + 1];
    for (int e = s + t; e < e_; e += 256) {
        int2 p = ebuf[e];
        int pos = atomicAdd(&lcur[p.y - (b << shift)], 1);
        csr[rowstart[p.y] + pos] = p.x;
    }
}

// ---------------- degree-scan (rowstart) ----------------

extern "C" __global__ void k_dinv(const int* __restrict__ deg, float* __restrict__ dinv, int n) {
    int i = blockIdx.x * 256 + threadIdx.x;
    if (i < n) dinv[i] = rsqrtf((float)(deg[i] + 1));   // +1 = self loop
}

extern "C" __global__ void k_scan_partial(const int* __restrict__ deg, int* __restrict__ bsum, int n) {
    int base = blockIdx.x * 1024;
    int s = 0;
    for (int i = threadIdx.x; i < 1024; i += 256) {
        int idx = base + i;
        s += (idx < n) ? deg[idx] : 0;
    }
    for (int off = 1; off < 64; off <<= 1) s += __shfl_xor(s, off, 64);
    __shared__ int wsum[4];
    if ((threadIdx.x & 63) == 0) wsum[threadIdx.x >> 6] = s;
    __syncthreads();
    if (threadIdx.x == 0) bsum[blockIdx.x] = wsum[0] + wsum[1] + wsum[2] + wsum[3];
}

extern "C" __global__ void k_scan_bsum(int* __restrict__ bsum, int nb) {
    if (threadIdx.x == 0 && blockIdx.x == 0) {
        int run = 0;
        for (int i = 0; i < nb; i++) { int v = bsum[i]; bsum[i] = run; run += v; }
    }
}

extern "C" __global__ void k_scan_write(const int* __restrict__ deg, const int* __restrict__ bsum,
                                        int* __restrict__ rowstart, int n) {
    int t = threadIdx.x;
    int base = blockIdx.x * 1024;
    int v[4], loc[4];
    int s = 0;
    #pragma unroll
    for (int i = 0; i < 4; i++) {
        int idx = base + t * 4 + i;
        v[i] = (idx < n) ? deg[idx] : 0;
        loc[i] = s; s += v[i];
    }
    __shared__ int sc[256];
    sc[t] = s;
    __syncthreads();
    int mine = s;
    for (int off = 1; off < 256; off <<= 1) {
        int add = (t >= off) ? sc[t - off] : 0;
        __syncthreads();
        sc[t] += add;
        __syncthreads();
    }
    int excl = sc[t] - mine + bsum[blockIdx.x];
    #pragma unroll
    for (int i = 0; i < 4; i++) {
        int idx = base + t * 4 + i;
        if (idx < n) rowstart[idx] = excl + loc[i];
    }
}

// ---------------- gemm1: h0s = (x@W1)*dinv ; r1 = silu(x@Wr1+br1) ----------------
// lane = row (64 rows/block), wave = 32-col slice (w0,w1 -> W1 cols 0-63;
// w2,w3 -> Wr1 cols 0-63). acc = 32 VGPRs. x: 1 scalar ds_read per k
// ([64][33] layout, (lane+k)%32 banks = 2-way = free). W: 8 uniform-address
// float4 loads per k (VMEM/SMEM pipe, L1/L2-resident). VALU-bound by design.
extern "C" __global__ __launch_bounds__(256) void k_gemm1(
    const float* __restrict__ x, const float* __restrict__ W1, const float* __restrict__ Wr1,
    const float* __restrict__ br1, const float* __restrict__ dinv,
    float* __restrict__ h0s, float* __restrict__ r1, int n)
{
    __shared__ float xs[64 * 33];
    int t = threadIdx.x;
    int lane = t & 63;
    int wv = __builtin_amdgcn_readfirstlane(t >> 6);   // wave id, compiler-uniform
    const float* Wp = (wv < 2) ? W1 : Wr1;
    const int c0 = (wv & 1) * 32;
    int r0 = blockIdx.x * 64;
    int row = r0 + lane;

    float acc[32] = {};

    for (int kk = 0; kk < 128; kk += 32) {
        if (kk) __syncthreads();
        #pragma unroll
        for (int i = 0; i < 2; i++) {              // stage 64 rows x 32 k (512 f4)
            int u = t + i * 256;
            int rr = u >> 3, kq = u & 7;
            float4 v = make_float4(0.f, 0.f, 0.f, 0.f);
            if (r0 + rr < n) v = *(const float4*)&x[(size_t)(r0 + rr) * 128 + kk + kq * 4];
            xs[rr * 33 + kq * 4 + 0] = v.x;
            xs[rr * 33 + kq * 4 + 1] = v.y;
            xs[rr * 33 + kq * 4 + 2] = v.z;
            xs[rr * 33 + kq * 4 + 3] = v.w;
        }
        __syncthreads();
        const float* xrow = &xs[lane * 33];
        #pragma unroll 8
        for (int k = 0; k < 32; k++) {
            float xv = xrow[k];
            const float* wrow = &Wp[(size_t)(kk + k) * 64 + c0];
            #pragma unroll
            for (int j = 0; j < 8; j++) {
                float4 w4 = *(const float4*)&wrow[j * 4];
                acc[j * 4 + 0] += xv * w4.x;
                acc[j * 4 + 1] += xv * w4.y;
                acc[j * 4 + 2] += xv * w4.z;
                acc[j * 4 + 3] += xv * w4.w;
            }
        }
    }

    if (row < n) {
        if (wv < 2) {                 // h0s cols c0..c0+31, prescaled by dinv
            float dv = dinv[row];
            #pragma unroll
            for (int j = 0; j < 8; j++) {
                float4 o = make_float4(acc[j*4+0]*dv, acc[j*4+1]*dv,
                                       acc[j*4+2]*dv, acc[j*4+3]*dv);
                *(float4*)&h0s[(size_t)row * 64 + c0 + j * 4] = o;
            }
        } else {                      // r1 cols c0..c0+31
            #pragma unroll
            for (int j = 0; j < 8; j++) {
                float4 b = *(const float4*)&br1[c0 + j * 4];
                float4 o = make_float4(silu_f(acc[j*4+0]+b.x), silu_f(acc[j*4+1]+b.y),
                                       silu_f(acc[j*4+2]+b.z), silu_f(acc[j*4+3]+b.w));
                *(float4*)&r1[(size_t)row * 64 + c0 + j * 4] = o;
            }
        }
    }
}

// h = silu(dinv[dst]*(sum_src h0s + h0s[dst]) + b1) + r1*alpha1 ; in place over r1
extern "C" __global__ __launch_bounds__(256) void k_agg1(
    const float* __restrict__ h0s, const int* __restrict__ rowstart, const int* __restrict__ deg,
    const int* __restrict__ csr, const float* __restrict__ dinv, const float* __restrict__ b1,
    const float* __restrict__ alpha1, float* __restrict__ r1h, int n)
{
    int wave = threadIdx.x >> 6, lane = threadIdx.x & 63;
    int node = blockIdx.x * 4 + wave;
    if (node >= n) return;
    int rs = rowstart[node];
    int cnt = deg[node];
    float acc = h0s[(size_t)node * 64 + lane];   // self loop
    int i = 0;
    for (; i + 8 <= cnt; i += 8) {
        int s0 = csr[rs+i+0], s1 = csr[rs+i+1], s2 = csr[rs+i+2], s3 = csr[rs+i+3];
        int s4 = csr[rs+i+4], s5 = csr[rs+i+5], s6 = csr[rs+i+6], s7 = csr[rs+i+7];
        float a0 = h0s[(size_t)s0*64+lane], a1 = h0s[(size_t)s1*64+lane];
        float a2 = h0s[(size_t)s2*64+lane], a3 = h0s[(size_t)s3*64+lane];
        float a4 = h0s[(size_t)s4*64+lane], a5 = h0s[(size_t)s5*64+lane];
        float a6 = h0s[(size_t)s6*64+lane], a7 = h0s[(size_t)s7*64+lane];
        acc += ((a0+a1)+(a2+a3)) + ((a4+a5)+(a6+a7));
    }
    for (; i < cnt; i++) acc += h0s[(size_t)csr[rs+i]*64+lane];
    float v = dinv[node] * acc + b1[lane];
    float hv = silu_f(v) + r1h[(size_t)node * 64 + lane] * alpha1[0];
    r1h[(size_t)node * 64 + lane] = hv;
}

// h2s = (h @ W2) * dinv ; r2 = silu(h @ Wr2 + br2)
extern "C" __global__ __launch_bounds__(256) void k_gemm2(
    const float* __restrict__ h, const float* __restrict__ W2, const float* __restrict__ Wr2,
    const float* __restrict__ br2, const float* __restrict__ dinv,
    float* __restrict__ h2s, float* __restrict__ r2, int n)
{
    __shared__ float xsT[64 * 132];   // [k][row]
    __shared__ float wsm[64 * 32];    // [k][c]
    int t = threadIdx.x;
    int r0 = blockIdx.x * 128;
    int rg = t >> 3;                  // 0..31, rows rg*4..+3
    int cg = t & 7;                   // cols cg*4..+3
    float acc[4][4] = {};

    #pragma unroll
    for (int i = 0; i < 8; i++) {     // stage h transposed: 2048 float4
        int u = t + i * 256;
        int row = u >> 4, kq = u & 15;
        float4 v = make_float4(0.f, 0.f, 0.f, 0.f);
        int grow = r0 + row;
        if (grow < n) v = *(const float4*)&h[(size_t)grow * 64 + kq * 4];
        xsT[(kq * 4 + 0) * 132 + row] = v.x;
        xsT[(kq * 4 + 1) * 132 + row] = v.y;
        xsT[(kq * 4 + 2) * 132 + row] = v.z;
        xsT[(kq * 4 + 3) * 132 + row] = v.w;
    }
    #pragma unroll
    for (int i = 0; i < 2; i++) {     // stage [W2|Wr2]: 512 float4
        int ul = t + i * 256;
        int k = ul >> 3, u = ul & 7;
        int c = u * 4;
        float4 v;
        if (c < 16) v = *(const float4*)&W2[(size_t)k * 16 + c];
        else        v = *(const float4*)&Wr2[(size_t)k * 16 + (c - 16)];
        *(float4*)&wsm[k * 32 + c] = v;
    }
    __syncthreads();

    const float* xbase = &xsT[rg * 4];
    const float* wbase = &wsm[cg * 4];
    #pragma unroll
    for (int k = 0; k < 64; k++) {
        float4 xa = *(const float4*)&xbase[k * 132];
        float4 wa = *(const float4*)&wbase[k * 32];
        float xv[4] = {xa.x, xa.y, xa.z, xa.w};
        float wv[4] = {wa.x, wa.y, wa.z, wa.w};
        #pragma unroll
        for (int i = 0; i < 4; i++)
            #pragma unroll
            for (int j = 0; j < 4; j++) acc[i][j] += xv[i] * wv[j];
    }

    if (cg < 4) {                     // h2s cols 0..15
        int c0 = cg * 4;
        #pragma unroll
        for (int i = 0; i < 4; i++) {
            int row = r0 + rg * 4 + i;
            if (row >= n) break;
            float dv = dinv[row];
            float4 o = make_float4(acc[i][0]*dv, acc[i][1]*dv, acc[i][2]*dv, acc[i][3]*dv);
            *(float4*)&h2s[(size_t)row * 16 + c0] = o;
        }
    } else {                          // r2 cols 0..15
        int c0 = (cg - 4) * 4;
        float4 b = *(const float4*)&br2[c0];
        #pragma unroll
        for (int i = 0; i < 4; i++) {
            int row = r0 + rg * 4 + i;
            if (row >= n) break;
            float4 o = make_float4(silu_f(acc[i][0]+b.x), silu_f(acc[i][1]+b.y),
                                   silu_f(acc[i][2]+b.z), silu_f(acc[i][3]+b.w));
            *(float4*)&r2[(size_t)row * 16 + c0] = o;
        }
    }
}

// z = dinv[dst]*(sum h2s + h2s[dst]) + b2 + r2*alpha2 ; in place over r2
extern "C" __global__ __launch_bounds__(256) void k_agg2(
    const float* __restrict__ h2s, const int* __restrict__ rowstart, const int* __restrict__ deg,
    const int* __restrict__ csr, const float* __restrict__ dinv, const float* __restrict__ b2,
    const float* __restrict__ alpha2, float* __restrict__ r2z, int n)
{
    int wave = threadIdx.x >> 6, lane = threadIdx.x & 63;
    int node = blockIdx.x * 4 + wave;
    if (node >= n) return;
    int rs = rowstart[node], cnt = deg[node];
    int sub = lane >> 4, j = lane & 15;
    float acc = 0.0f;
    int i = sub;
    for (; i + 8 <= cnt; i += 8) {
        int sa = csr[rs + i], sb = csr[rs + i + 4];
        acc += h2s[(size_t)sa * 16 + j] + h2s[(size_t)sb * 16 + j];
    }
    for (; i < cnt; i += 4) acc += h2s[(size_t)csr[rs + i] * 16 + j];
    acc += __shfl_xor(acc, 16, 64);
    acc += __shfl_xor(acc, 32, 64);
    if (sub == 0) {
        acc += h2s[(size_t)node * 16 + j];
        float v = dinv[node] * acc + b2[j] + r2z[(size_t)node * 16 + j] * alpha2[0];
        r2z[(size_t)node * 16 + j] = v;
    }
}

// graph mean pool
extern "C" __global__ __launch_bounds__(256) void k_pool(
    const float* __restrict__ z, const int* __restrict__ batch, float* __restrict__ emb, int n)
{
    int g = blockIdx.x;
    int lo = 0, hi = n;
    while (lo < hi) { int m = (lo + hi) >> 1; if (batch[m] < g) lo = m + 1; else hi = m; }
    int start = lo;
    lo = start; hi = n;
    while (lo < hi) { int m = (lo + hi) >> 1; if (batch[m] < g + 1) lo = m + 1; else hi = m; }
    int end = lo;
    int j = threadIdx.x & 15, grp = threadIdx.x >> 4;
    float acc = 0.0f;
    for (int r = start + grp; r < end; r += 16) acc += z[(size_t)r * 16 + j];
    __shared__ float part[16][17];
    part[grp][j] = acc;
    __syncthreads();
    if (threadIdx.x < 16) {
        float s = 0.0f;
        #pragma unroll
        for (int q = 0; q < 16; q++) s += part[q][threadIdx.x];
        float cnt = (float)(end - start);
        emb[g * 16 + threadIdx.x] = s / fmaxf(cnt, 1.0f);
    }
}

extern "C" __global__ void k_metrics(
    const float* __restrict__ tol, const float* __restrict__ cost,
    const float* __restrict__ time_, const float* __restrict__ qty,
    const float* __restrict__ mW1, const float* __restrict__ mb1,
    const float* __restrict__ mW2, const float* __restrict__ mb2,
    float* __restrict__ metrics)
{
    int t = threadIdx.x;
    if (t >= 64) return;
    int i = t >> 4, j = t & 15;
    float mv = (i == 0) ? tol[0] : (i == 1) ? cost[0] : (i == 2) ? time_[0] : qty[0];
    float acc = mb2[i * 16 + j];
    #pragma unroll
    for (int k = 0; k < 8; k++) {
        float hpre = mv * mW1[i * 8 + k] + mb1[i * 8 + k];
        acc += silu_f(hpre) * mW2[i * 128 + k * 16 + j];
    }
    metrics[t] = acc;
}

extern "C" __global__ __launch_bounds__(128) void k_head(
    const float* __restrict__ emb, const float* __restrict__ metrics,
    const float* __restrict__ Wf1, const float* __restrict__ bf1,
    const float* __restrict__ Wf2, const float* __restrict__ bf2,
    float* __restrict__ out, int NC)
{
    int g = blockIdx.x;
    __shared__ float c[80], hidden[80];
    int t = threadIdx.x;
    if (t < 16) c[t] = emb[g * 16 + t];
    else if (t < 80) c[t] = metrics[t - 16];
    __syncthreads();
    if (t < 80) {
        float acc = bf1[t];
        #pragma unroll 8
        for (int k = 0; k < 80; k++) acc += c[k] * Wf1[k * 80 + t];
        hidden[t] = silu_f(acc);
    }
    __syncthreads();
    if (t < NC) {
        float acc = bf2[t];
        #pragma unroll 8
        for (int k = 0; k < 80; k++) acc += hidden[k] * Wf2[k * NC + t];
        out[g * NC + t] = acc;
    }
}

extern "C" void kernel_launch(void* const* d_in, const int* in_sizes, int n_in,
                              void* d_out, int out_size, void* d_ws, size_t ws_size,
                              hipStream_t stream)
{
    const float* x     = (const float*)d_in[0];
    const int*   ei    = (const int*)d_in[1];
    const int*   batch = (const int*)d_in[2];
    const float* tol   = (const float*)d_in[3];
    const float* cost  = (const float*)d_in[4];
    const float* time_ = (const float*)d_in[5];
    const float* qty   = (const float*)d_in[6];
    const float* W1    = (const float*)d_in[7];
    const float* b1    = (const float*)d_in[8];
    const float* W2    = (const float*)d_in[9];
    const float* b2    = (const float*)d_in[10];
    const float* Wr1   = (const float*)d_in[11];
    const float* br1   = (const float*)d_in[12];
    const float* Wr2   = (const float*)d_in[13];
    const float* br2   = (const float*)d_in[14];
    const float* alpha1= (const float*)d_in[15];
    const float* alpha2= (const float*)d_in[16];
    const float* mW1   = (const float*)d_in[17];
    const float* mb1   = (const float*)d_in[18];
    const float* mW2   = (const float*)d_in[19];
    const float* mb2   = (const float*)d_in[20];
    const float* Wf1   = (const float*)d_in[21];
    const float* bf1   = (const float*)d_in[22];
    const float* Wf2   = (const float*)d_in[23];
    const float* bf2   = (const float*)d_in[24];

    const int N  = in_sizes[2];
    const int E  = in_sizes[1] / 2;
    const int NC = in_sizes[24];
    const int G  = out_size / NC;

    const int* srcIdx = ei;
    const int* dstIdx = ei + E;

    int shift = 8;
    while (((N + (1 << shift) - 1) >> shift) > 512) shift++;
    const int nbkt = (N + (1 << shift) - 1) >> shift;

    char* w = (char*)d_ws;
    auto alloc = [&](size_t bytes) { char* p = w; w += (bytes + 255) & ~(size_t)255; return p; };
    int*   deg      = (int*)alloc((size_t)N * 4);
    int*   rowstart = (int*)alloc((size_t)N * 4);
    int*   bcount   = (int*)alloc(2048);
    int*   boff     = (int*)alloc(2052 + 252);
    int*   bcursor  = (int*)alloc(2048);
    int*   bsum     = (int*)alloc(4096);
    int*   csr      = (int*)alloc((size_t)E * 4);
    int2*  ebuf     = (int2*)alloc((size_t)E * 8);
    float* dinv     = (float*)alloc((size_t)N * 4);
    float* bufA     = (float*)alloc((size_t)N * 64 * 4);  // h0s, later h2s
    float* bufB     = (float*)alloc((size_t)N * 64 * 4);  // r1, later h (in place)
    float* bufC     = (float*)alloc((size_t)N * 16 * 4);  // r2, later z (in place)
    float* emb      = (float*)alloc((size_t)G * 16 * 4);
    float* metricsv = (float*)alloc(256);

    hipMemsetAsync(bcount, 0, 2048, stream);

    int EB8 = (E + 8191) / 8192;
    int nb  = (N + 255) / 256;
    int NB  = (N + 1023) / 1024;

    k_bhist   <<<EB8, 256, 0, stream>>>(dstIdx, bcount, E, nbkt, shift);
    k_bscan   <<<1, 512, 0, stream>>>(bcount, boff, bcursor, nbkt);
    k_bscatter<<<EB8, 256, 0, stream>>>(srcIdx, dstIdx, bcursor, ebuf, E, nbkt, shift);
    k_bdeg    <<<nbkt, 256, 0, stream>>>(ebuf, boff, deg, shift, N);
    k_dinv    <<<nb, 256, 0, stream>>>(deg, dinv, N);
    k_scan_partial<<<NB, 256, 0, stream>>>(deg, bsum, N);
    k_scan_bsum   <<<1, 64, 0, stream>>>(bsum, NB);
    k_scan_write  <<<NB, 256, 0, stream>>>(deg, bsum, rowstart, N);
    k_bfill   <<<nbkt, 256, 0, stream>>>(ebuf, boff, rowstart, csr, shift);

    k_gemm1<<<(N + 63) / 64, 256, 0, stream>>>(x, W1, Wr1, br1, dinv, bufA, bufB, N);
    k_agg1 <<<(N + 3) / 4, 256, 0, stream>>>(bufA, rowstart, deg, csr, dinv, b1, alpha1, bufB, N);
    k_gemm2<<<(N + 127) / 128, 256, 0, stream>>>(bufB, W2, Wr2, br2, dinv, bufA, bufC, N);
    k_agg2 <<<(N + 3) / 4, 256, 0, stream>>>(bufA, rowstart, deg, csr, dinv, b2, alpha2, bufC, N);
    k_pool <<<G, 256, 0, stream>>>(bufC, batch, emb, N);
    k_metrics<<<1, 64, 0, stream>>>(tol, cost, time_, qty, mW1, mb1, mW2, mb2, metricsv);
    k_head <<<G, 128, 0, stream>>>(emb, metricsv, Wf1, bf1, Wf2, bf2, (float*)d_out, NC);
}

// Round 9
// 289.480 us; speedup vs baseline: 2.1191x; 1.0732x over previous
//
#include <hip/hip_runtime.h>

static __device__ __forceinline__ float silu_f(float v) {
    return v / (1.0f + __expf(-v));
}

// ---------------- bucketed CSR build ----------------

extern "C" __global__ __launch_bounds__(256) void k_bhist(
    const int* __restrict__ dst, int* __restrict__ bcount, int E, int nbkt, int shift)
{
    __shared__ int lh[512];
    int t = threadIdx.x;
    for (int i = t; i < 512; i += 256) lh[i] = 0;
    __syncthreads();
    int e0 = blockIdx.x * 8192;
    #pragma unroll 4
    for (int i = 0; i < 32; i++) {
        int e = e0 + t + i * 256;
        if (e < E) atomicAdd(&lh[dst[e] >> shift], 1);
    }
    __syncthreads();
    for (int b = t; b < nbkt; b += 256)
        if (lh[b]) atomicAdd(&bcount[b], lh[b]);
}

extern "C" __global__ __launch_bounds__(512) void k_bscan(
    const int* __restrict__ bcount, int* __restrict__ boff, int* __restrict__ bcursor, int nbkt)
{
    __shared__ int sc[512];
    int t = threadIdx.x;
    int v = (t < nbkt) ? bcount[t] : 0;
    sc[t] = v;
    __syncthreads();
    for (int off = 1; off < 512; off <<= 1) {
        int add = (t >= off) ? sc[t - off] : 0;
        __syncthreads();
        sc[t] += add;
        __syncthreads();
    }
    int excl = sc[t] - v;
    if (t < nbkt) { boff[t] = excl; bcursor[t] = excl; }
    if (t == nbkt - 1) boff[nbkt] = excl + v;
}

extern "C" __global__ __launch_bounds__(256) void k_bscatter(
    const int* __restrict__ src, const int* __restrict__ dst, int* __restrict__ bcursor,
    int2* __restrict__ ebuf, int E, int nbkt, int shift)
{
    __shared__ int lh[512];
    __shared__ int lbase[512];
    int t = threadIdx.x;
    for (int i = t; i < 512; i += 256) lh[i] = 0;
    __syncthreads();
    int e0 = blockIdx.x * 8192;
    #pragma unroll 4
    for (int i = 0; i < 32; i++) {
        int e = e0 + t + i * 256;
        if (e < E) atomicAdd(&lh[dst[e] >> shift], 1);
    }
    __syncthreads();
    for (int b = t; b < nbkt; b += 256)
        lbase[b] = lh[b] ? atomicAdd(&bcursor[b], lh[b]) : 0;
    __syncthreads();
    #pragma unroll 4
    for (int i = 0; i < 32; i++) {
        int e = e0 + t + i * 256;
        if (e < E) {
            int d = dst[e];
            int p = atomicAdd(&lbase[d >> shift], 1);
            ebuf[p] = make_int2(src[e], d);
        }
    }
}

// deg + dinv + rowstart in one pass: rowstart = boff[b] + intra-bucket prefix.
extern "C" __global__ __launch_bounds__(256) void k_bdeg_scan(
    const int2* __restrict__ ebuf, const int* __restrict__ boff,
    int* __restrict__ deg, float* __restrict__ dinv, int* __restrict__ rowstart,
    int shift, int N)
{
    int b = blockIdx.x;
    int W = 1 << shift;
    __shared__ int lcur[4096];
    __shared__ int sc[256];
    int t = threadIdx.x;
    for (int i = t; i < W; i += 256) lcur[i] = 0;
    __syncthreads();
    int s = boff[b], e_ = boff[b + 1];
    for (int e = s + t; e < e_; e += 256)
        atomicAdd(&lcur[ebuf[e].y - (b << shift)], 1);
    __syncthreads();

    int c = W >> 8;                 // elements per thread (>=1 since shift>=8)
    int base = t * c;
    int mysum = 0;
    for (int i = 0; i < c; i++) mysum += lcur[base + i];
    sc[t] = mysum;
    __syncthreads();
    int mine = mysum;
    for (int off = 1; off < 256; off <<= 1) {
        int add = (t >= off) ? sc[t - off] : 0;
        __syncthreads();
        sc[t] += add;
        __syncthreads();
    }
    int run = sc[t] - mine + s;     // exclusive prefix + bucket edge base
    int nbase = b << shift;
    for (int i = 0; i < c; i++) {
        int d = lcur[base + i];
        int node = nbase + base + i;
        if (node < N) {
            rowstart[node] = run;
            deg[node] = d;
            dinv[node] = rsqrtf((float)(d + 1));   // +1 self loop
        }
        run += d;
    }
}

extern "C" __global__ __launch_bounds__(256) void k_bfill(
    const int2* __restrict__ ebuf, const int* __restrict__ boff,
    const int* __restrict__ rowstart, int* __restrict__ csr, int shift)
{
    int b = blockIdx.x;
    int W = 1 << shift;
    __shared__ int lcur[4096];
    int t = threadIdx.x;
    for (int i = t; i < W; i += 256) lcur[i] = 0;
    __syncthreads();
    int s = boff[b], e_ = boff[b + 1];
    for (int e = s + t; e < e_; e += 256) {
        int2 p = ebuf[e];
        int pos = atomicAdd(&lcur[p.y - (b << shift)], 1);
        csr[rowstart[p.y] + pos] = p.x;
    }
}

// ---------------- gemm1: h0s = (x@W1)*dinv ; r1 = silu(x@Wr1+br1) ----------------
// 128 rows/block, 256 threads; lane owns rows (lane, lane+64); wave = 32-col slice
// (w0,w1 -> W1, w2,w3 -> Wr1; uniform via readfirstlane). Per k: 2 ds_read_b32
// (2-way bank alias = free) + 8 uniform s_load float4 + 64 FMA -> W-load stall
// amortized 2x vs R8. acc = 64 VGPR, total ~100 < 128 cap.
extern "C" __global__ __launch_bounds__(256) void k_gemm1(
    const float* __restrict__ x, const float* __restrict__ W1, const float* __restrict__ Wr1,
    const float* __restrict__ br1, const float* __restrict__ dinv,
    float* __restrict__ h0s, float* __restrict__ r1, int n)
{
    __shared__ float xs[128 * 33];
    int t = threadIdx.x;
    int lane = t & 63;
    int wv = __builtin_amdgcn_readfirstlane(t >> 6);
    const float* Wp = (wv < 2) ? W1 : Wr1;
    const int c0 = (wv & 1) * 32;
    int r0 = blockIdx.x * 128;

    float acc0[32] = {}, acc1[32] = {};

    for (int kk = 0; kk < 128; kk += 32) {
        if (kk) __syncthreads();
        #pragma unroll
        for (int i = 0; i < 4; i++) {              // stage 128 rows x 32 k (1024 f4)
            int u = t + i * 256;
            int rr = u >> 3, kq = u & 7;
            float4 v = make_float4(0.f, 0.f, 0.f, 0.f);
            if (r0 + rr < n) v = *(const float4*)&x[(size_t)(r0 + rr) * 128 + kk + kq * 4];
            xs[rr * 33 + kq * 4 + 0] = v.x;
            xs[rr * 33 + kq * 4 + 1] = v.y;
            xs[rr * 33 + kq * 4 + 2] = v.z;
            xs[rr * 33 + kq * 4 + 3] = v.w;
        }
        __syncthreads();
        const float* xr0 = &xs[lane * 33];
        const float* xr1 = &xs[(lane + 64) * 33];
        #pragma unroll 4
        for (int k = 0; k < 32; k++) {
            float xv0 = xr0[k];
            float xv1 = xr1[k];
            const float* wrow = &Wp[(size_t)(kk + k) * 64 + c0];
            #pragma unroll
            for (int j = 0; j < 8; j++) {
                float4 w4 = *(const float4*)&wrow[j * 4];
                acc0[j*4+0] += xv0 * w4.x; acc1[j*4+0] += xv1 * w4.x;
                acc0[j*4+1] += xv0 * w4.y; acc1[j*4+1] += xv1 * w4.y;
                acc0[j*4+2] += xv0 * w4.z; acc1[j*4+2] += xv1 * w4.z;
                acc0[j*4+3] += xv0 * w4.w; acc1[j*4+3] += xv1 * w4.w;
            }
        }
    }

    #pragma unroll
    for (int half = 0; half < 2; half++) {
        int row = r0 + half * 64 + lane;
        if (row >= n) continue;
        const float* a = half ? acc1 : acc0;
        if (wv < 2) {                 // h0s cols c0..c0+31, prescaled by dinv
            float dv = dinv[row];
            #pragma unroll
            for (int j = 0; j < 8; j++) {
                float4 o = make_float4(a[j*4+0]*dv, a[j*4+1]*dv, a[j*4+2]*dv, a[j*4+3]*dv);
                *(float4*)&h0s[(size_t)row * 64 + c0 + j * 4] = o;
            }
        } else {                      // r1 cols c0..c0+31
            #pragma unroll
            for (int j = 0; j < 8; j++) {
                float4 b = *(const float4*)&br1[c0 + j * 4];
                float4 o = make_float4(silu_f(a[j*4+0]+b.x), silu_f(a[j*4+1]+b.y),
                                       silu_f(a[j*4+2]+b.z), silu_f(a[j*4+3]+b.w));
                *(float4*)&r1[(size_t)row * 64 + c0 + j * 4] = o;
            }
        }
    }
}

// h = silu(dinv[dst]*(sum_src h0s + h0s[dst]) + b1) + r1*alpha1 ; in place over r1
extern "C" __global__ __launch_bounds__(256) void k_agg1(
    const float* __restrict__ h0s, const int* __restrict__ rowstart, const int* __restrict__ deg,
    const int* __restrict__ csr, const float* __restrict__ dinv, const float* __restrict__ b1,
    const float* __restrict__ alpha1, float* __restrict__ r1h, int n)
{
    int wave = threadIdx.x >> 6, lane = threadIdx.x & 63;
    int node = blockIdx.x * 4 + wave;
    if (node >= n) return;
    int rs = rowstart[node];
    int cnt = deg[node];
    float acc = h0s[(size_t)node * 64 + lane];   // self loop
    int i = 0;
    for (; i + 8 <= cnt; i += 8) {
        int s0 = csr[rs+i+0], s1 = csr[rs+i+1], s2 = csr[rs+i+2], s3 = csr[rs+i+3];
        int s4 = csr[rs+i+4], s5 = csr[rs+i+5], s6 = csr[rs+i+6], s7 = csr[rs+i+7];
        float a0 = h0s[(size_t)s0*64+lane], a1 = h0s[(size_t)s1*64+lane];
        float a2 = h0s[(size_t)s2*64+lane], a3 = h0s[(size_t)s3*64+lane];
        float a4 = h0s[(size_t)s4*64+lane], a5 = h0s[(size_t)s5*64+lane];
        float a6 = h0s[(size_t)s6*64+lane], a7 = h0s[(size_t)s7*64+lane];
        acc += ((a0+a1)+(a2+a3)) + ((a4+a5)+(a6+a7));
    }
    for (; i < cnt; i++) acc += h0s[(size_t)csr[rs+i]*64+lane];
    float v = dinv[node] * acc + b1[lane];
    float hv = silu_f(v) + r1h[(size_t)node * 64 + lane] * alpha1[0];
    r1h[(size_t)node * 64 + lane] = hv;
}

// h2s = (h @ W2) * dinv ; r2 = silu(h @ Wr2 + br2)
extern "C" __global__ __launch_bounds__(256) void k_gemm2(
    const float* __restrict__ h, const float* __restrict__ W2, const float* __restrict__ Wr2,
    const float* __restrict__ br2, const float* __restrict__ dinv,
    float* __restrict__ h2s, float* __restrict__ r2, int n)
{
    __shared__ float xsT[64 * 132];   // [k][row]
    __shared__ float wsm[64 * 32];    // [k][c]
    int t = threadIdx.x;
    int r0 = blockIdx.x * 128;
    int rg = t >> 3;                  // 0..31, rows rg*4..+3
    int cg = t & 7;                   // cols cg*4..+3
    float acc[4][4] = {};

    #pragma unroll
    for (int i = 0; i < 8; i++) {     // stage h transposed: 2048 float4
        int u = t + i * 256;
        int row = u >> 4, kq = u & 15;
        float4 v = make_float4(0.f, 0.f, 0.f, 0.f);
        int grow = r0 + row;
        if (grow < n) v = *(const float4*)&h[(size_t)grow * 64 + kq * 4];
        xsT[(kq * 4 + 0) * 132 + row] = v.x;
        xsT[(kq * 4 + 1) * 132 + row] = v.y;
        xsT[(kq * 4 + 2) * 132 + row] = v.z;
        xsT[(kq * 4 + 3) * 132 + row] = v.w;
    }
    #pragma unroll
    for (int i = 0; i < 2; i++) {     // stage [W2|Wr2]: 512 float4
        int ul = t + i * 256;
        int k = ul >> 3, u = ul & 7;
        int c = u * 4;
        float4 v;
        if (c < 16) v = *(const float4*)&W2[(size_t)k * 16 + c];
        else        v = *(const float4*)&Wr2[(size_t)k * 16 + (c - 16)];
        *(float4*)&wsm[k * 32 + c] = v;
    }
    __syncthreads();

    const float* xbase = &xsT[rg * 4];
    const float* wbase = &wsm[cg * 4];
    #pragma unroll
    for (int k = 0; k < 64; k++) {
        float4 xa = *(const float4*)&xbase[k * 132];
        float4 wa = *(const float4*)&wbase[k * 32];
        float xv[4] = {xa.x, xa.y, xa.z, xa.w};
        float wv[4] = {wa.x, wa.y, wa.z, wa.w};
        #pragma unroll
        for (int i = 0; i < 4; i++)
            #pragma unroll
            for (int j = 0; j < 4; j++) acc[i][j] += xv[i] * wv[j];
    }

    if (cg < 4) {                     // h2s cols 0..15
        int c0 = cg * 4;
        #pragma unroll
        for (int i = 0; i < 4; i++) {
            int row = r0 + rg * 4 + i;
            if (row >= n) break;
            float dv = dinv[row];
            float4 o = make_float4(acc[i][0]*dv, acc[i][1]*dv, acc[i][2]*dv, acc[i][3]*dv);
            *(float4*)&h2s[(size_t)row * 16 + c0] = o;
        }
    } else {                          // r2 cols 0..15
        int c0 = (cg - 4) * 4;
        float4 b = *(const float4*)&br2[c0];
        #pragma unroll
        for (int i = 0; i < 4; i++) {
            int row = r0 + rg * 4 + i;
            if (row >= n) break;
            float4 o = make_float4(silu_f(acc[i][0]+b.x), silu_f(acc[i][1]+b.y),
                                   silu_f(acc[i][2]+b.z), silu_f(acc[i][3]+b.w));
            *(float4*)&r2[(size_t)row * 16 + c0] = o;
        }
    }
}

// z = dinv[dst]*(sum h2s + h2s[dst]) + b2 + r2*alpha2 ; in place over r2
extern "C" __global__ __launch_bounds__(256) void k_agg2(
    const float* __restrict__ h2s, const int* __restrict__ rowstart, const int* __restrict__ deg,
    const int* __restrict__ csr, const float* __restrict__ dinv, const float* __restrict__ b2,
    const float* __restrict__ alpha2, float* __restrict__ r2z, int n)
{
    int wave = threadIdx.x >> 6, lane = threadIdx.x & 63;
    int node = blockIdx.x * 4 + wave;
    if (node >= n) return;
    int rs = rowstart[node], cnt = deg[node];
    int sub = lane >> 4, j = lane & 15;
    float acc = 0.0f;
    int i = sub;
    for (; i + 8 <= cnt; i += 8) {
        int sa = csr[rs + i], sb = csr[rs + i + 4];
        acc += h2s[(size_t)sa * 16 + j] + h2s[(size_t)sb * 16 + j];
    }
    for (; i < cnt; i += 4) acc += h2s[(size_t)csr[rs + i] * 16 + j];
    acc += __shfl_xor(acc, 16, 64);
    acc += __shfl_xor(acc, 32, 64);
    if (sub == 0) {
        acc += h2s[(size_t)node * 16 + j];
        float v = dinv[node] * acc + b2[j] + r2z[(size_t)node * 16 + j] * alpha2[0];
        r2z[(size_t)node * 16 + j] = v;
    }
}

// fused pool + metrics MLP + classifier head; one block per graph
extern "C" __global__ __launch_bounds__(256) void k_poolhead(
    const float* __restrict__ z, const int* __restrict__ batch,
    const float* __restrict__ tol, const float* __restrict__ cost,
    const float* __restrict__ time_, const float* __restrict__ qty,
    const float* __restrict__ mW1, const float* __restrict__ mb1,
    const float* __restrict__ mW2, const float* __restrict__ mb2,
    const float* __restrict__ Wf1, const float* __restrict__ bf1,
    const float* __restrict__ Wf2, const float* __restrict__ bf2,
    float* __restrict__ out, int n, int NC)
{
    int g = blockIdx.x;
    __shared__ float comb[80];        // [emb(16) | metrics(64)]
    __shared__ float part[16][17];
    __shared__ float hidden[80];
    int t = threadIdx.x;

    int lo = 0, hi = n;
    while (lo < hi) { int m = (lo + hi) >> 1; if (batch[m] < g) lo = m + 1; else hi = m; }
    int start = lo;
    lo = start; hi = n;
    while (lo < hi) { int m = (lo + hi) >> 1; if (batch[m] < g + 1) lo = m + 1; else hi = m; }
    int end = lo;

    int j = t & 15, grp = t >> 4;
    float acc = 0.0f;
    for (int r = start + grp; r < end; r += 16) acc += z[(size_t)r * 16 + j];
    part[grp][j] = acc;
    __syncthreads();
    if (t < 16) {
        float s = 0.0f;
        #pragma unroll
        for (int q = 0; q < 16; q++) s += part[q][t];
        comb[t] = s / fmaxf((float)(end - start), 1.0f);
    } else if (t >= 64 && t < 128) {  // metrics MLP on threads 64..127
        int tt = t - 64;
        int i = tt >> 4, jj = tt & 15;
        float mv = (i == 0) ? tol[0] : (i == 1) ? cost[0] : (i == 2) ? time_[0] : qty[0];
        float a = mb2[i * 16 + jj];
        #pragma unroll
        for (int k = 0; k < 8; k++) {
            float hpre = mv * mW1[i * 8 + k] + mb1[i * 8 + k];
            a += silu_f(hpre) * mW2[i * 128 + k * 16 + jj];
        }
        comb[16 + tt] = a;
    }
    __syncthreads();
    if (t < 80) {
        float a = bf1[t];
        #pragma unroll 8
        for (int k = 0; k < 80; k++) a += comb[k] * Wf1[k * 80 + t];
        hidden[t] = silu_f(a);
    }
    __syncthreads();
    if (t < NC) {
        float a = bf2[t];
        #pragma unroll 8
        for (int k = 0; k < 80; k++) a += hidden[k] * Wf2[k * NC + t];
        out[g * NC + t] = a;
    }
}

extern "C" void kernel_launch(void* const* d_in, const int* in_sizes, int n_in,
                              void* d_out, int out_size, void* d_ws, size_t ws_size,
                              hipStream_t stream)
{
    const float* x     = (const float*)d_in[0];
    const int*   ei    = (const int*)d_in[1];
    const int*   batch = (const int*)d_in[2];
    const float* tol   = (const float*)d_in[3];
    const float* cost  = (const float*)d_in[4];
    const float* time_ = (const float*)d_in[5];
    const float* qty   = (const float*)d_in[6];
    const float* W1    = (const float*)d_in[7];
    const float* b1    = (const float*)d_in[8];
    const float* W2    = (const float*)d_in[9];
    const float* b2    = (const float*)d_in[10];
    const float* Wr1   = (const float*)d_in[11];
    const float* br1   = (const float*)d_in[12];
    const float* Wr2   = (const float*)d_in[13];
    const float* br2   = (const float*)d_in[14];
    const float* alpha1= (const float*)d_in[15];
    const float* alpha2= (const float*)d_in[16];
    const float* mW1   = (const float*)d_in[17];
    const float* mb1   = (const float*)d_in[18];
    const float* mW2   = (const float*)d_in[19];
    const float* mb2   = (const float*)d_in[20];
    const float* Wf1   = (const float*)d_in[21];
    const float* bf1   = (const float*)d_in[22];
    const float* Wf2   = (const float*)d_in[23];
    const float* bf2   = (const float*)d_in[24];

    const int N  = in_sizes[2];
    const int E  = in_sizes[1] / 2;
    const int NC = in_sizes[24];
    const int G  = out_size / NC;

    const int* srcIdx = ei;
    const int* dstIdx = ei + E;

    int shift = 8;
    while (((N + (1 << shift) - 1) >> shift) > 512) shift++;
    const int nbkt = (N + (1 << shift) - 1) >> shift;

    char* w = (char*)d_ws;
    auto alloc = [&](size_t bytes) { char* p = w; w += (bytes + 255) & ~(size_t)255; return p; };
    int*   deg      = (int*)alloc((size_t)N * 4);
    int*   rowstart = (int*)alloc((size_t)N * 4);
    int*   bcount   = (int*)alloc(2048);
    int*   boff     = (int*)alloc(2052 + 252);
    int*   bcursor  = (int*)alloc(2048);
    int*   csr      = (int*)alloc((size_t)E * 4);
    int2*  ebuf     = (int2*)alloc((size_t)E * 8);
    float* dinv     = (float*)alloc((size_t)N * 4);
    float* bufA     = (float*)alloc((size_t)N * 64 * 4);  // h0s, later h2s
    float* bufB     = (float*)alloc((size_t)N * 64 * 4);  // r1, later h (in place)
    float* bufC     = (float*)alloc((size_t)N * 16 * 4);  // r2, later z (in place)

    hipMemsetAsync(bcount, 0, 2048, stream);

    int EB8 = (E + 8191) / 8192;

    k_bhist    <<<EB8, 256, 0, stream>>>(dstIdx, bcount, E, nbkt, shift);
    k_bscan    <<<1, 512, 0, stream>>>(bcount, boff, bcursor, nbkt);
    k_bscatter <<<EB8, 256, 0, stream>>>(srcIdx, dstIdx, bcursor, ebuf, E, nbkt, shift);
    k_bdeg_scan<<<nbkt, 256, 0, stream>>>(ebuf, boff, deg, dinv, rowstart, shift, N);
    k_bfill    <<<nbkt, 256, 0, stream>>>(ebuf, boff, rowstart, csr, shift);

    k_gemm1<<<(N + 127) / 128, 256, 0, stream>>>(x, W1, Wr1, br1, dinv, bufA, bufB, N);
    k_agg1 <<<(N + 3) / 4, 256, 0, stream>>>(bufA, rowstart, deg, csr, dinv, b1, alpha1, bufB, N);
    k_gemm2<<<(N + 127) / 128, 256, 0, stream>>>(bufB, W2, Wr2, br2, dinv, bufA, bufC, N);
    k_agg2 <<<(N + 3) / 4, 256, 0, stream>>>(bufA, rowstart, deg, csr, dinv, b2, alpha2, bufC, N);
    k_poolhead<<<G, 256, 0, stream>>>(bufC, batch, tol, cost, time_, qty,
                                      mW1, mb1, mW2, mb2, Wf1, bf1, Wf2, bf2,
                                      (float*)d_out, N, NC);
}